// Round 5
// baseline (104.504 us; speedup 1.0000x reference)
//
#include <hip/hip_runtime.h>

#define HW1 16384   // 128*128
#define HW2 4096    // 64*64
#define HW3 1024    // 32*32
#define NB  4
#define NCH 256

typedef float f4 __attribute__((ext_vector_type(4)));

__device__ inline float4 f4add(float4 a, float4 b) {
    a.x += b.x; a.y += b.y; a.z += b.z; a.w += b.w; return a;
}

// clamp-to-edge half-pixel bilinear sample of an n x n map at output coord (y,x)
__device__ inline float bil(const float* m, int n, int y, int x, float scl, float off) {
    float fy = y * scl - off, fx = x * scl - off;
    float fy0 = floorf(fy), fx0 = floorf(fx);
    float wy = fy - fy0, wx = fx - fx0;
    int y0 = max((int)fy0, 0), y1 = min((int)fy0 + 1, n - 1);
    int x0 = max((int)fx0, 0), x1 = min((int)fx0 + 1, n - 1);
    float a = m[y0 * n + x0] * (1.f - wx) + m[y0 * n + x1] * wx;
    float b = m[y1 * n + x0] * (1.f - wx) + m[y1 * n + x1] * wx;
    return a * (1.f - wy) + b * wy;
}

// Channel sums of t0_l1 (128x128), t0_l2 (64x64), t0_l3 (32x32).
__global__ __launch_bounds__(256) void k_sums(
    const float* __restrict__ l1, const float* __restrict__ l2, const float* __restrict__ l3,
    float* __restrict__ SUM1, float* __restrict__ S2, float* __restrict__ S3) {
    __shared__ float4 red[256];
    int t = threadIdx.x, s = t >> 5, g = t & 31;
    int blk = blockIdx.x;
    const float* src; float* dst; int hw; int gg;
    if (blk < 512) {
        gg = blk * 32 + g; int p4 = gg * 4;
        int b = p4 >> 14, off = p4 & (HW1 - 1);
        src = l1 + ((size_t)(b * NCH + s * 32)) * HW1 + off; dst = SUM1; hw = HW1;
    } else if (blk < 640) {
        gg = (blk - 512) * 32 + g; int p4 = gg * 4;
        int b = p4 >> 12, off = p4 & (HW2 - 1);
        src = l2 + ((size_t)(b * NCH + s * 32)) * HW2 + off; dst = S2; hw = HW2;
    } else {
        gg = (blk - 640) * 32 + g; int p4 = gg * 4;
        int b = p4 >> 10, off = p4 & (HW3 - 1);
        src = l3 + ((size_t)(b * NCH + s * 32)) * HW3 + off; dst = S3; hw = HW3;
    }
    float4 acc = make_float4(0.f, 0.f, 0.f, 0.f);
    #pragma unroll 8
    for (int c = 0; c < 32; ++c)
        acc = f4add(acc, *(const float4*)(src + (size_t)c * hw));
    red[t] = acc;
    __syncthreads();
    if (s < 4) red[t] = f4add(red[t], red[t + 128]);
    __syncthreads();
    if (s < 2) red[t] = f4add(red[t], red[t + 64]);
    __syncthreads();
    if (s == 0) {
        float4 r = f4add(red[t], red[t + 32]);
        ((float4*)dst)[gg] = r;
    }
}

// One block (256 thr) per output row n = b'*64 + q'.
__global__ __launch_bounds__(256) void k_query(
    const float* __restrict__ SUM1, const float* __restrict__ S2, const float* __restrict__ S3,
    const float* __restrict__ qb,
    const float* __restrict__ ow1, const float* __restrict__ ob1,
    const float* __restrict__ ow2, const float* __restrict__ ob2,
    const float* __restrict__ sw1, const float* __restrict__ sb1,
    const float* __restrict__ sw2, const float* __restrict__ sb2,
    int* __restrict__ RS, int* __restrict__ CS, float* __restrict__ SC) {
    __shared__ float feat[256];
    __shared__ float hid[256];
    __shared__ float res[3];
    int n = blockIdx.x, t = threadIdx.x;
    int b = n & 3, qp = n >> 2;
    int qi = qp >> 3, qj = qp & 7;
    {
        int i = t >> 4, j = t & 15;
        int y = 16 * qi + i, x = 16 * qj + j;
        float v = SUM1[b * HW1 + y * 128 + x];
        v += bil(S2 + b * HW2, 64, y, x, 0.5f, 0.25f);
        v += bil(S3 + b * HW3, 32, y, x, 0.25f, 0.375f);
        feat[t] = v * (1.0f / 768.0f);
    }
    __syncthreads();
    {
        int h = t & 127;
        const float* W  = (t < 128) ? ow1 : sw1;
        const float* Bv = (t < 128) ? ob1 : sb1;
        float acc = 0.f;
        #pragma unroll 8
        for (int d = 0; d < 256; ++d)
            acc = fmaf(feat[d], W[d * 128 + h], acc);
        hid[t] = fmaxf(acc + Bv[h], 0.f);
    }
    __syncthreads();
    int w = t >> 6, l = t & 63;
    if (w < 3) {
        float acc;
        if (w == 0)      acc = fmaf(hid[l], ow2[2 * l],     hid[l + 64] * ow2[2 * l + 128]);
        else if (w == 1) acc = fmaf(hid[l], ow2[2 * l + 1], hid[l + 64] * ow2[2 * l + 129]);
        else             acc = fmaf(hid[128 + l], sw2[l],   hid[192 + l] * sw2[l + 64]);
        #pragma unroll
        for (int off = 32; off; off >>= 1) acc += __shfl_down(acc, off);
        if (l == 0) res[w] = acc + (w == 0 ? ob2[0] : (w == 1 ? ob2[1] : sb2[0]));
    }
    __syncthreads();
    if (t == 0) {
        int q = n & 63;
        int cpx = (int)(qb[2 * q + 0] * 128.0f);
        int cpy = (int)(qb[2 * q + 1] * 128.0f);
        int cpsx = (int)((float)cpx + res[0] * 8.0f);
        int cpsy = (int)((float)cpy + res[1] * 8.0f);
        RS[n] = cpsx - 8;
        CS[n] = cpsy - 8;
        SC[n] = res[2];
    }
}

__global__ __launch_bounds__(256) void k_scalemap(
    const int* __restrict__ RS, const int* __restrict__ CS, const float* __restrict__ SC,
    float* __restrict__ SMAP) {
    __shared__ int rs[64], cs[64];
    __shared__ float sc[64];
    int t = threadIdx.x;
    int p = blockIdx.x * 256 + t;
    int b = p >> 14;
    if (t < 64) { rs[t] = RS[b * 64 + t]; cs[t] = CS[b * 64 + t]; sc[t] = SC[b * 64 + t]; }
    __syncthreads();
    int off = p & (HW1 - 1);
    int r = off >> 7, c = off & 127;
    float sv = 1.0f;
    for (int q = 63; q >= 0; --q) {
        int r0 = rs[q], c0 = cs[q];
        if (r0 >= 0 && c0 >= 0 && (unsigned)(r - r0) < 16u && (unsigned)(c - c0) < 16u) {
            sv = sc[q]; break;
        }
    }
    SMAP[p] = sv;
}

// Persistent balanced k_out with async-stage prefetch (T14):
// phase-1 source tiles load into regs BEFORE phase-0 streaming; phase-2 tiles
// load during phase 1. Phase 0 batched 2-deep for MLP.
__global__ __launch_bounds__(256, 4) void k_out(
    const float* __restrict__ a1, const float* __restrict__ a2, const float* __restrict__ a3,
    const float* __restrict__ n1, const float* __restrict__ n2, const float* __restrict__ n3,
    const float* __restrict__ SMAP, float* __restrict__ out) {
    __shared__ float cur[4096];
    __shared__ float nxt[4096];
    int t = threadIdx.x;
    int c_local = blockIdx.x >> 2;
    int b = blockIdx.x & 3;
    const f4* s4 = (const f4*)(SMAP + b * HW1);
    const size_t obase = (size_t)(b * 768) * HW1;

    // ---- prefetch phase-1 tiles into registers (issued before phase 0) ----
    const f4* p1c = (const f4*)(a2 + ((size_t)(b * 256 + c_local)) * HW2);
    const f4* p1n = (const f4*)(n2 + ((size_t)(b * 256 + c_local)) * HW2);
    f4 pc0 = p1c[t],       pc1 = p1c[t + 256], pc2 = p1c[t + 512], pc3 = p1c[t + 768];
    f4 pn0 = __builtin_nontemporal_load(&p1n[t]);
    f4 pn1 = __builtin_nontemporal_load(&p1n[t + 256]);
    f4 pn2 = __builtin_nontemporal_load(&p1n[t + 512]);
    f4 pn3 = __builtin_nontemporal_load(&p1n[t + 768]);

    // ---- phase 0: direct channel c_local, 2-deep batched streaming ----
    {
        const f4* f  = (const f4*)(a1 + ((size_t)(b * 256 + c_local)) * HW1);
        const f4* fn = (const f4*)(n1 + ((size_t)(b * 256 + c_local)) * HW1);
        f4* o4 = (f4*)(out + obase + (size_t)c_local * HW1);
        #pragma unroll
        for (int base = 0; base < 4096; base += 512) {
            int i0 = base + t, i1 = base + t + 256;
            f4 fv0 = f[i0];
            f4 fv1 = f[i1];
            f4 nv0 = __builtin_nontemporal_load(&fn[i0]);
            f4 nv1 = __builtin_nontemporal_load(&fn[i1]);
            f4 sv0 = s4[i0];
            f4 sv1 = s4[i1];
            f4 r0, r1;
            r0.x = fmaf(fv0.x, sv0.x, nv0.x);
            r0.y = fmaf(fv0.y, sv0.y, nv0.y);
            r0.z = fmaf(fv0.z, sv0.z, nv0.z);
            r0.w = fmaf(fv0.w, sv0.w, nv0.w);
            r1.x = fmaf(fv1.x, sv1.x, nv1.x);
            r1.y = fmaf(fv1.y, sv1.y, nv1.y);
            r1.z = fmaf(fv1.z, sv1.z, nv1.z);
            r1.w = fmaf(fv1.w, sv1.w, nv1.w);
            __builtin_nontemporal_store(r0, &o4[i0]);
            __builtin_nontemporal_store(r1, &o4[i1]);
        }
    }

    // ---- commit phase-1 tiles to LDS (loads long since in flight) ----
    ((f4*)cur)[t]       = pc0; ((f4*)cur)[t + 256] = pc1;
    ((f4*)cur)[t + 512] = pc2; ((f4*)cur)[t + 768] = pc3;
    ((f4*)nxt)[t]       = pn0; ((f4*)nxt)[t + 256] = pn1;
    ((f4*)nxt)[t + 512] = pn2; ((f4*)nxt)[t + 768] = pn3;
    __syncthreads();

    // ---- prefetch phase-2 tiles into registers ----
    const f4* p2c = (const f4*)(a3 + ((size_t)(b * 256 + c_local)) * HW3);
    const f4* p2n = (const f4*)(n3 + ((size_t)(b * 256 + c_local)) * HW3);
    f4 qc = p2c[t];
    f4 qn = __builtin_nontemporal_load(&p2n[t]);

    // ---- phase 1: 2x upsample channel 256 + c_local ----
    {
        f4* o4 = (f4*)(out + obase + (size_t)(256 + c_local) * HW1);
        for (int i = t; i < 4096; i += 256) {
            int y = i >> 5, j = i & 31;
            int iy = (y - 1) >> 1;
            int y0 = max(iy, 0), y1 = min(iy + 1, 63);
            float wy = (y & 1) ? 0.25f : 0.75f;
            int cm1 = max(2 * j - 1, 0);
            int c0 = 2 * j, c1 = 2 * j + 1;
            int c2c = min(2 * j + 2, 63);
            const float* r0 = cur + y0 * 64; const float* r1 = cur + y1 * 64;
            const float* u0 = nxt + y0 * 64; const float* u1 = nxt + y1 * 64;
            float a0 = r0[cm1], a1v = r0[c0], a2v = r0[c1], a3v = r0[c2c];
            float b0 = r1[cm1], b1v = r1[c0], b2v = r1[c1], b3v = r1[c2c];
            float p0 = u0[cm1], p1 = u0[c0], p2 = u0[c1], p3 = u0[c2c];
            float q0 = u1[cm1], q1 = u1[c0], q2 = u1[c1], q3 = u1[c2c];
            float h0 = fmaf(0.25f, a0, 0.75f * a1v);
            float h1 = fmaf(0.75f, a1v, 0.25f * a2v);
            float h2 = fmaf(0.25f, a1v, 0.75f * a2v);
            float h3 = fmaf(0.75f, a2v, 0.25f * a3v);
            float g0 = fmaf(0.25f, b0, 0.75f * b1v);
            float g1 = fmaf(0.75f, b1v, 0.25f * b2v);
            float g2 = fmaf(0.25f, b1v, 0.75f * b2v);
            float g3 = fmaf(0.75f, b2v, 0.25f * b3v);
            float e0 = fmaf(0.25f, p0, 0.75f * p1);
            float e1 = fmaf(0.75f, p1, 0.25f * p2);
            float e2 = fmaf(0.25f, p1, 0.75f * p2);
            float e3 = fmaf(0.75f, p2, 0.25f * p3);
            float k0 = fmaf(0.25f, q0, 0.75f * q1);
            float k1 = fmaf(0.75f, q1, 0.25f * q2);
            float k2 = fmaf(0.25f, q1, 0.75f * q2);
            float k3 = fmaf(0.75f, q2, 0.25f * q3);
            f4 sv = s4[i];
            f4 r;
            r.x = fmaf(fmaf(g0 - h0, wy, h0), sv.x, fmaf(k0 - e0, wy, e0));
            r.y = fmaf(fmaf(g1 - h1, wy, h1), sv.y, fmaf(k1 - e1, wy, e1));
            r.z = fmaf(fmaf(g2 - h2, wy, h2), sv.z, fmaf(k2 - e2, wy, e2));
            r.w = fmaf(fmaf(g3 - h3, wy, h3), sv.w, fmaf(k3 - e3, wy, e3));
            __builtin_nontemporal_store(r, &o4[i]);
        }
    }

    __syncthreads();   // all reads of cur/nxt done before phase-2 restage
    ((f4*)cur)[t] = qc;
    ((f4*)nxt)[t] = qn;
    __syncthreads();

    // ---- phase 2: 4x upsample channel 512 + c_local ----
    {
        f4* o4 = (f4*)(out + obase + (size_t)(512 + c_local) * HW1);
        for (int i = t; i < 4096; i += 256) {
            int y = i >> 5, j = i & 31;
            int iy = (y - 2) >> 2;
            int y0 = max(iy, 0), y1 = min(iy + 1, 31);
            int ym = y & 3;
            float wy = (ym < 2) ? (0.625f + 0.25f * ym) : (0.25f * ym - 0.375f);
            int cm1 = max(j - 1, 0);
            int c0 = j, c1 = min(j + 1, 31);
            const float* r0 = cur + y0 * 32; const float* r1 = cur + y1 * 32;
            const float* u0 = nxt + y0 * 32; const float* u1 = nxt + y1 * 32;
            float a0 = r0[cm1], a1v = r0[c0], a2v = r0[c1];
            float b0 = r1[cm1], b1v = r1[c0], b2v = r1[c1];
            float p0 = u0[cm1], p1 = u0[c0], p2 = u0[c1];
            float q0 = u1[cm1], q1 = u1[c0], q2 = u1[c1];
            float h0 = fmaf(0.375f, a0, 0.625f * a1v);
            float h1 = fmaf(0.125f, a0, 0.875f * a1v);
            float h2 = fmaf(0.875f, a1v, 0.125f * a2v);
            float h3 = fmaf(0.625f, a1v, 0.375f * a2v);
            float g0 = fmaf(0.375f, b0, 0.625f * b1v);
            float g1 = fmaf(0.125f, b0, 0.875f * b1v);
            float g2 = fmaf(0.875f, b1v, 0.125f * b2v);
            float g3 = fmaf(0.625f, b1v, 0.375f * b2v);
            float e0 = fmaf(0.375f, p0, 0.625f * p1);
            float e1 = fmaf(0.125f, p0, 0.875f * p1);
            float e2 = fmaf(0.875f, p1, 0.125f * p2);
            float e3 = fmaf(0.625f, p1, 0.375f * p2);
            float k0 = fmaf(0.375f, q0, 0.625f * q1);
            float k1 = fmaf(0.125f, q0, 0.875f * q1);
            float k2 = fmaf(0.875f, q1, 0.125f * q2);
            float k3 = fmaf(0.625f, q1, 0.375f * q2);
            f4 sv = s4[i];
            f4 r;
            r.x = fmaf(fmaf(g0 - h0, wy, h0), sv.x, fmaf(k0 - e0, wy, e0));
            r.y = fmaf(fmaf(g1 - h1, wy, h1), sv.y, fmaf(k1 - e1, wy, e1));
            r.z = fmaf(fmaf(g2 - h2, wy, h2), sv.z, fmaf(k2 - e2, wy, e2));
            r.w = fmaf(fmaf(g3 - h3, wy, h3), sv.w, fmaf(k3 - e3, wy, e3));
            __builtin_nontemporal_store(r, &o4[i]);
        }
    }
}

extern "C" void kernel_launch(void* const* d_in, const int* in_sizes, int n_in,
                              void* d_out, int out_size, void* d_ws, size_t ws_size,
                              hipStream_t stream) {
    (void)in_sizes; (void)n_in; (void)out_size; (void)ws_size;
    const float* t0_l1 = (const float*)d_in[1];
    const float* t0_l2 = (const float*)d_in[2];
    const float* t0_l3 = (const float*)d_in[3];
    const float* t1_l1 = (const float*)d_in[5];
    const float* t1_l2 = (const float*)d_in[6];
    const float* t1_l3 = (const float*)d_in[7];
    const float* qb    = (const float*)d_in[8];
    const float* ow1   = (const float*)d_in[9];
    const float* ob1   = (const float*)d_in[10];
    const float* ow2   = (const float*)d_in[11];
    const float* ob2   = (const float*)d_in[12];
    const float* sw1   = (const float*)d_in[13];
    const float* sb1   = (const float*)d_in[14];
    const float* sw2   = (const float*)d_in[15];
    const float* sb2   = (const float*)d_in[16];

    char* ws = (char*)d_ws;
    float* SUM1 = (float*)(ws + 0);
    float* S2   = (float*)(ws + 262144);
    float* S3   = (float*)(ws + 327680);
    int*   RS   = (int*)  (ws + 344064);
    int*   CS   = (int*)  (ws + 345088);
    float* SC   = (float*)(ws + 346112);
    float* SMAP = (float*)(ws + 347136);
    float* out  = (float*)d_out;

    hipLaunchKernelGGL(k_sums, dim3(672), dim3(256), 0, stream,
                       t0_l1, t0_l2, t0_l3, SUM1, S2, S3);
    hipLaunchKernelGGL(k_query, dim3(256), dim3(256), 0, stream,
                       SUM1, S2, S3, qb, ow1, ob1, ow2, ob2, sw1, sb1, sw2, sb2, RS, CS, SC);
    hipLaunchKernelGGL(k_scalemap, dim3(256), dim3(256), 0, stream, RS, CS, SC, SMAP);
    hipLaunchKernelGGL(k_out, dim3(1024), dim3(256), 0, stream,
                       t0_l1, t0_l2, t0_l3, t1_l1, t1_l2, t1_l3, SMAP, out);
}

// Round 6
// 103.332 us; speedup vs baseline: 1.0113x; 1.0113x over previous
//
#include <hip/hip_runtime.h>

#define HW1 16384   // 128*128
#define HW2 4096    // 64*64
#define HW3 1024    // 32*32
#define NB  4
#define NCH 256

typedef float f4 __attribute__((ext_vector_type(4)));

__device__ inline float4 f4add(float4 a, float4 b) {
    a.x += b.x; a.y += b.y; a.z += b.z; a.w += b.w; return a;
}

// clamp-to-edge half-pixel bilinear sample of an n x n map at output coord (y,x)
__device__ inline float bil(const float* m, int n, int y, int x, float scl, float off) {
    float fy = y * scl - off, fx = x * scl - off;
    float fy0 = floorf(fy), fx0 = floorf(fx);
    float wy = fy - fy0, wx = fx - fx0;
    int y0 = max((int)fy0, 0), y1 = min((int)fy0 + 1, n - 1);
    int x0 = max((int)fx0, 0), x1 = min((int)fx0 + 1, n - 1);
    float a = m[y0 * n + x0] * (1.f - wx) + m[y0 * n + x1] * wx;
    float b = m[y1 * n + x0] * (1.f - wx) + m[y1 * n + x1] * wx;
    return a * (1.f - wy) + b * wy;
}

// Channel sums of t0_l1 (128x128), t0_l2 (64x64), t0_l3 (32x32).
__global__ __launch_bounds__(256) void k_sums(
    const float* __restrict__ l1, const float* __restrict__ l2, const float* __restrict__ l3,
    float* __restrict__ SUM1, float* __restrict__ S2, float* __restrict__ S3) {
    __shared__ float4 red[256];
    int t = threadIdx.x, s = t >> 5, g = t & 31;
    int blk = blockIdx.x;
    const float* src; float* dst; int hw; int gg;
    if (blk < 512) {
        gg = blk * 32 + g; int p4 = gg * 4;
        int b = p4 >> 14, off = p4 & (HW1 - 1);
        src = l1 + ((size_t)(b * NCH + s * 32)) * HW1 + off; dst = SUM1; hw = HW1;
    } else if (blk < 640) {
        gg = (blk - 512) * 32 + g; int p4 = gg * 4;
        int b = p4 >> 12, off = p4 & (HW2 - 1);
        src = l2 + ((size_t)(b * NCH + s * 32)) * HW2 + off; dst = S2; hw = HW2;
    } else {
        gg = (blk - 640) * 32 + g; int p4 = gg * 4;
        int b = p4 >> 10, off = p4 & (HW3 - 1);
        src = l3 + ((size_t)(b * NCH + s * 32)) * HW3 + off; dst = S3; hw = HW3;
    }
    float4 acc = make_float4(0.f, 0.f, 0.f, 0.f);
    #pragma unroll 8
    for (int c = 0; c < 32; ++c)
        acc = f4add(acc, *(const float4*)(src + (size_t)c * hw));
    red[t] = acc;
    __syncthreads();
    if (s < 4) red[t] = f4add(red[t], red[t + 128]);
    __syncthreads();
    if (s < 2) red[t] = f4add(red[t], red[t + 64]);
    __syncthreads();
    if (s == 0) {
        float4 r = f4add(red[t], red[t + 32]);
        ((float4*)dst)[gg] = r;
    }
}

// One block (256 thr) per output row n = b'*64 + q'.
__global__ __launch_bounds__(256) void k_query(
    const float* __restrict__ SUM1, const float* __restrict__ S2, const float* __restrict__ S3,
    const float* __restrict__ qb,
    const float* __restrict__ ow1, const float* __restrict__ ob1,
    const float* __restrict__ ow2, const float* __restrict__ ob2,
    const float* __restrict__ sw1, const float* __restrict__ sb1,
    const float* __restrict__ sw2, const float* __restrict__ sb2,
    int* __restrict__ RS, int* __restrict__ CS, float* __restrict__ SC) {
    __shared__ float feat[256];
    __shared__ float hid[256];
    __shared__ float res[3];
    int n = blockIdx.x, t = threadIdx.x;
    int b = n & 3, qp = n >> 2;
    int qi = qp >> 3, qj = qp & 7;
    {
        int i = t >> 4, j = t & 15;
        int y = 16 * qi + i, x = 16 * qj + j;
        float v = SUM1[b * HW1 + y * 128 + x];
        v += bil(S2 + b * HW2, 64, y, x, 0.5f, 0.25f);
        v += bil(S3 + b * HW3, 32, y, x, 0.25f, 0.375f);
        feat[t] = v * (1.0f / 768.0f);
    }
    __syncthreads();
    {
        int h = t & 127;
        const float* W  = (t < 128) ? ow1 : sw1;
        const float* Bv = (t < 128) ? ob1 : sb1;
        float acc = 0.f;
        #pragma unroll 8
        for (int d = 0; d < 256; ++d)
            acc = fmaf(feat[d], W[d * 128 + h], acc);
        hid[t] = fmaxf(acc + Bv[h], 0.f);
    }
    __syncthreads();
    int w = t >> 6, l = t & 63;
    if (w < 3) {
        float acc;
        if (w == 0)      acc = fmaf(hid[l], ow2[2 * l],     hid[l + 64] * ow2[2 * l + 128]);
        else if (w == 1) acc = fmaf(hid[l], ow2[2 * l + 1], hid[l + 64] * ow2[2 * l + 129]);
        else             acc = fmaf(hid[128 + l], sw2[l],   hid[192 + l] * sw2[l + 64]);
        #pragma unroll
        for (int off = 32; off; off >>= 1) acc += __shfl_down(acc, off);
        if (l == 0) res[w] = acc + (w == 0 ? ob2[0] : (w == 1 ? ob2[1] : sb2[0]));
    }
    __syncthreads();
    if (t == 0) {
        int q = n & 63;
        int cpx = (int)(qb[2 * q + 0] * 128.0f);
        int cpy = (int)(qb[2 * q + 1] * 128.0f);
        int cpsx = (int)((float)cpx + res[0] * 8.0f);
        int cpsy = (int)((float)cpy + res[1] * 8.0f);
        RS[n] = cpsx - 8;
        CS[n] = cpsy - 8;
        SC[n] = res[2];
    }
}

__global__ __launch_bounds__(256) void k_scalemap(
    const int* __restrict__ RS, const int* __restrict__ CS, const float* __restrict__ SC,
    float* __restrict__ SMAP) {
    __shared__ int rs[64], cs[64];
    __shared__ float sc[64];
    int t = threadIdx.x;
    int p = blockIdx.x * 256 + t;
    int b = p >> 14;
    if (t < 64) { rs[t] = RS[b * 64 + t]; cs[t] = CS[b * 64 + t]; sc[t] = SC[b * 64 + t]; }
    __syncthreads();
    int off = p & (HW1 - 1);
    int r = off >> 7, c = off & 127;
    float sv = 1.0f;
    for (int q = 63; q >= 0; --q) {
        int r0 = rs[q], c0 = cs[q];
        if (r0 >= 0 && c0 >= 0 && (unsigned)(r - r0) < 16u && (unsigned)(c - c0) < 16u) {
            sv = sc[q]; break;
        }
    }
    SMAP[p] = sv;
}

// Upsample-only kernel: 1024 blocks, each does one 2x plane + one 4x plane
// sharing (c_local, b). LDS/VALU-heavy; runs while t0_l2/l3 are L3-hot.
__global__ __launch_bounds__(256, 4) void k_up(
    const float* __restrict__ a2, const float* __restrict__ a3,
    const float* __restrict__ n2, const float* __restrict__ n3,
    const float* __restrict__ SMAP, float* __restrict__ out) {
    __shared__ float cur[4096];
    __shared__ float nxt[4096];
    int t = threadIdx.x;
    int c_local = blockIdx.x >> 2;
    int b = blockIdx.x & 3;
    const f4* s4 = (const f4*)(SMAP + b * HW1);
    const size_t obase = (size_t)(b * 768) * HW1;

    // ---- 2x upsample channel 256 + c_local ----
    {
        const f4* s0 = (const f4*)(a2 + ((size_t)(b * 256 + c_local)) * HW2);
        const f4* s1 = (const f4*)(n2 + ((size_t)(b * 256 + c_local)) * HW2);
        f4* o4 = (f4*)(out + obase + (size_t)(256 + c_local) * HW1);
        for (int i = t; i < 1024; i += 256) {
            ((f4*)cur)[i] = s0[i];
            ((f4*)nxt)[i] = __builtin_nontemporal_load(&s1[i]);
        }
        __syncthreads();
        for (int i = t; i < 4096; i += 256) {
            int y = i >> 5, j = i & 31;
            int iy = (y - 1) >> 1;
            int y0 = max(iy, 0), y1 = min(iy + 1, 63);
            float wy = (y & 1) ? 0.25f : 0.75f;
            int cm1 = max(2 * j - 1, 0);
            int c0 = 2 * j, c1 = 2 * j + 1;
            int c2c = min(2 * j + 2, 63);
            const float* r0 = cur + y0 * 64; const float* r1 = cur + y1 * 64;
            const float* u0 = nxt + y0 * 64; const float* u1 = nxt + y1 * 64;
            float a0 = r0[cm1], a1v = r0[c0], a2v = r0[c1], a3v = r0[c2c];
            float b0 = r1[cm1], b1v = r1[c0], b2v = r1[c1], b3v = r1[c2c];
            float p0 = u0[cm1], p1 = u0[c0], p2 = u0[c1], p3 = u0[c2c];
            float q0 = u1[cm1], q1 = u1[c0], q2 = u1[c1], q3 = u1[c2c];
            float h0 = fmaf(0.25f, a0, 0.75f * a1v);
            float h1 = fmaf(0.75f, a1v, 0.25f * a2v);
            float h2 = fmaf(0.25f, a1v, 0.75f * a2v);
            float h3 = fmaf(0.75f, a2v, 0.25f * a3v);
            float g0 = fmaf(0.25f, b0, 0.75f * b1v);
            float g1 = fmaf(0.75f, b1v, 0.25f * b2v);
            float g2 = fmaf(0.25f, b1v, 0.75f * b2v);
            float g3 = fmaf(0.75f, b2v, 0.25f * b3v);
            float e0 = fmaf(0.25f, p0, 0.75f * p1);
            float e1 = fmaf(0.75f, p1, 0.25f * p2);
            float e2 = fmaf(0.25f, p1, 0.75f * p2);
            float e3 = fmaf(0.75f, p2, 0.25f * p3);
            float k0 = fmaf(0.25f, q0, 0.75f * q1);
            float k1 = fmaf(0.75f, q1, 0.25f * q2);
            float k2 = fmaf(0.25f, q1, 0.75f * q2);
            float k3 = fmaf(0.75f, q2, 0.25f * q3);
            f4 sv = s4[i];
            f4 r;
            r.x = fmaf(fmaf(g0 - h0, wy, h0), sv.x, fmaf(k0 - e0, wy, e0));
            r.y = fmaf(fmaf(g1 - h1, wy, h1), sv.y, fmaf(k1 - e1, wy, e1));
            r.z = fmaf(fmaf(g2 - h2, wy, h2), sv.z, fmaf(k2 - e2, wy, e2));
            r.w = fmaf(fmaf(g3 - h3, wy, h3), sv.w, fmaf(k3 - e3, wy, e3));
            __builtin_nontemporal_store(r, &o4[i]);
        }
    }

    __syncthreads();   // all reads of cur/nxt done before restage

    // ---- 4x upsample channel 512 + c_local ----
    {
        const f4* s0 = (const f4*)(a3 + ((size_t)(b * 256 + c_local)) * HW3);
        const f4* s1 = (const f4*)(n3 + ((size_t)(b * 256 + c_local)) * HW3);
        f4* o4 = (f4*)(out + obase + (size_t)(512 + c_local) * HW1);
        for (int i = t; i < 256; i += 256) {
            ((f4*)cur)[i] = s0[i];
            ((f4*)nxt)[i] = __builtin_nontemporal_load(&s1[i]);
        }
        __syncthreads();
        for (int i = t; i < 4096; i += 256) {
            int y = i >> 5, j = i & 31;
            int iy = (y - 2) >> 2;
            int y0 = max(iy, 0), y1 = min(iy + 1, 31);
            int ym = y & 3;
            float wy = (ym < 2) ? (0.625f + 0.25f * ym) : (0.25f * ym - 0.375f);
            int cm1 = max(j - 1, 0);
            int c0 = j, c1 = min(j + 1, 31);
            const float* r0 = cur + y0 * 32; const float* r1 = cur + y1 * 32;
            const float* u0 = nxt + y0 * 32; const float* u1 = nxt + y1 * 32;
            float a0 = r0[cm1], a1v = r0[c0], a2v = r0[c1];
            float b0 = r1[cm1], b1v = r1[c0], b2v = r1[c1];
            float p0 = u0[cm1], p1 = u0[c0], p2 = u0[c1];
            float q0 = u1[cm1], q1 = u1[c0], q2 = u1[c1];
            float h0 = fmaf(0.375f, a0, 0.625f * a1v);
            float h1 = fmaf(0.125f, a0, 0.875f * a1v);
            float h2 = fmaf(0.875f, a1v, 0.125f * a2v);
            float h3 = fmaf(0.625f, a1v, 0.375f * a2v);
            float g0 = fmaf(0.375f, b0, 0.625f * b1v);
            float g1 = fmaf(0.125f, b0, 0.875f * b1v);
            float g2 = fmaf(0.875f, b1v, 0.125f * b2v);
            float g3 = fmaf(0.625f, b1v, 0.375f * b2v);
            float e0 = fmaf(0.375f, p0, 0.625f * p1);
            float e1 = fmaf(0.125f, p0, 0.875f * p1);
            float e2 = fmaf(0.875f, p1, 0.125f * p2);
            float e3 = fmaf(0.625f, p1, 0.375f * p2);
            float k0 = fmaf(0.375f, q0, 0.625f * q1);
            float k1 = fmaf(0.125f, q0, 0.875f * q1);
            float k2 = fmaf(0.875f, q1, 0.125f * q2);
            float k3 = fmaf(0.625f, q1, 0.375f * q2);
            f4 sv = s4[i];
            f4 r;
            r.x = fmaf(fmaf(g0 - h0, wy, h0), sv.x, fmaf(k0 - e0, wy, e0));
            r.y = fmaf(fmaf(g1 - h1, wy, h1), sv.y, fmaf(k1 - e1, wy, e1));
            r.z = fmaf(fmaf(g2 - h2, wy, h2), sv.z, fmaf(k2 - e2, wy, e2));
            r.w = fmaf(fmaf(g3 - h3, wy, h3), sv.w, fmaf(k3 - e3, wy, e3));
            __builtin_nontemporal_store(r, &o4[i]);
        }
    }
}

// Direct-channel streaming kernel: 2048 blocks x 256 thr, half a plane each.
// No LDS -> 8 blocks/CU, pure BW.
__global__ __launch_bounds__(256) void k_direct(
    const float* __restrict__ a1, const float* __restrict__ n1,
    const float* __restrict__ SMAP, float* __restrict__ out) {
    int t = threadIdx.x;
    int plane = blockIdx.x >> 1;
    int half  = blockIdx.x & 1;
    int b  = plane >> 8;
    int ch = plane & 255;
    const f4* f  = (const f4*)(a1 + ((size_t)(b * 256 + ch)) * HW1);
    const f4* fn = (const f4*)(n1 + ((size_t)(b * 256 + ch)) * HW1);
    const f4* s4 = (const f4*)(SMAP + b * HW1);
    f4* o4 = (f4*)(out + ((size_t)(b * 768 + ch)) * HW1);
    int base = half * 2048;
    #pragma unroll
    for (int k = 0; k < 8; ++k) {
        int i = base + k * 256 + t;
        f4 fv = f[i];
        f4 sv = s4[i];
        f4 nv = __builtin_nontemporal_load(&fn[i]);
        f4 r;
        r.x = fmaf(fv.x, sv.x, nv.x);
        r.y = fmaf(fv.y, sv.y, nv.y);
        r.z = fmaf(fv.z, sv.z, nv.z);
        r.w = fmaf(fv.w, sv.w, nv.w);
        __builtin_nontemporal_store(r, &o4[i]);
    }
}

extern "C" void kernel_launch(void* const* d_in, const int* in_sizes, int n_in,
                              void* d_out, int out_size, void* d_ws, size_t ws_size,
                              hipStream_t stream) {
    (void)in_sizes; (void)n_in; (void)out_size; (void)ws_size;
    const float* t0_l1 = (const float*)d_in[1];
    const float* t0_l2 = (const float*)d_in[2];
    const float* t0_l3 = (const float*)d_in[3];
    const float* t1_l1 = (const float*)d_in[5];
    const float* t1_l2 = (const float*)d_in[6];
    const float* t1_l3 = (const float*)d_in[7];
    const float* qb    = (const float*)d_in[8];
    const float* ow1   = (const float*)d_in[9];
    const float* ob1   = (const float*)d_in[10];
    const float* ow2   = (const float*)d_in[11];
    const float* ob2   = (const float*)d_in[12];
    const float* sw1   = (const float*)d_in[13];
    const float* sb1   = (const float*)d_in[14];
    const float* sw2   = (const float*)d_in[15];
    const float* sb2   = (const float*)d_in[16];

    char* ws = (char*)d_ws;
    float* SUM1 = (float*)(ws + 0);
    float* S2   = (float*)(ws + 262144);
    float* S3   = (float*)(ws + 327680);
    int*   RS   = (int*)  (ws + 344064);
    int*   CS   = (int*)  (ws + 345088);
    float* SC   = (float*)(ws + 346112);
    float* SMAP = (float*)(ws + 347136);
    float* out  = (float*)d_out;

    hipLaunchKernelGGL(k_sums, dim3(672), dim3(256), 0, stream,
                       t0_l1, t0_l2, t0_l3, SUM1, S2, S3);
    hipLaunchKernelGGL(k_query, dim3(256), dim3(256), 0, stream,
                       SUM1, S2, S3, qb, ow1, ob1, ow2, ob2, sw1, sb1, sw2, sb2, RS, CS, SC);
    hipLaunchKernelGGL(k_scalemap, dim3(256), dim3(256), 0, stream, RS, CS, SC, SMAP);
    hipLaunchKernelGGL(k_up, dim3(1024), dim3(256), 0, stream,
                       t0_l2, t0_l3, t1_l2, t1_l3, SMAP, out);
    hipLaunchKernelGGL(k_direct, dim3(2048), dim3(256), 0, stream,
                       t0_l1, t1_l1, SMAP, out);
}